// Round 2
// baseline (703.942 us; speedup 1.0000x reference)
//
#include <hip/hip_runtime.h>

// Adaptive avg pool (16,2048,64,64) fp32 -> (16,2048,6,6).
// Column-sum formulation: one wave per plane, lane = column.
//   Phase A: 68 fully-coalesced global_load_dword (64 rows + 4 overlap rows,
//            compile-time bin edges, unrolled) accumulate acc[6] h-bin sums
//            per column in registers.
//   Phase B: 1.6 KiB/wave LDS transpose (stride 67: 6 bin-rows land on
//            distinct bank offsets, only free 2-way aliasing), 36 lanes
//            reduce 11-12 columns per w-bin, scale, store.
// 4 independent waves (planes) per 256-thread block; 8 blocks/CU = 32 waves/CU.

#define HW 64
#define NOUT 6
#define LSTR 67   // 6 rows * 67 floats; i*67 mod 32 = 3i -> banks all distinct

__global__ __launch_bounds__(256, 8)
void adaptive_pool_kernel(const float* __restrict__ x, float* __restrict__ out) {
    __shared__ float col[4][NOUT * LSTR];   // ~6.4 KiB total

    const int wave = threadIdx.x >> 6;
    const int lane = threadIdx.x & 63;
    const int plane = blockIdx.x * 4 + wave;
    const float* __restrict__ src = x + (size_t)plane * (HW * HW) + lane;

    const int bs[NOUT] = {0, 10, 21, 32, 42, 53};
    const int be[NOUT] = {11, 22, 32, 43, 54, 64};

    // ---- Phase A: per-column h-bin sums (compile-time unrolled, 68 loads) ----
    float acc[NOUT];
    #pragma unroll
    for (int i = 0; i < NOUT; ++i) {
        float s = 0.f;
        #pragma unroll
        for (int h = bs[i]; h < be[i]; ++h)
            s += src[h * HW];
        acc[i] = s;
    }

    #pragma unroll
    for (int i = 0; i < NOUT; ++i)
        col[wave][i * LSTR + lane] = acc[i];
    __syncthreads();

    // ---- Phase B: w-bin reduction, 36 lanes per wave ----
    if (lane < NOUT * NOUT) {
        int i = lane / NOUT;
        int j = lane - i * NOUT;
        const float* c = &col[wave][i * LSTR];
        float s = 0.f;
        for (int w = bs[j]; w < be[j]; ++w)
            s += c[w];
        float scale = 1.0f / (float)((be[i] - bs[i]) * (be[j] - bs[j]));
        out[(size_t)plane * (NOUT * NOUT) + lane] = s * scale;
    }
}

extern "C" void kernel_launch(void* const* d_in, const int* in_sizes, int n_in,
                              void* d_out, int out_size, void* d_ws, size_t ws_size,
                              hipStream_t stream) {
    const float* x = (const float*)d_in[0];
    float* out = (float*)d_out;
    const int n_planes = in_sizes[0] / (HW * HW);      // 32768
    adaptive_pool_kernel<<<n_planes / 4, 256, 0, stream>>>(x, out);
}

// Round 3
// 667.716 us; speedup vs baseline: 1.0543x; 1.0543x over previous
//
#include <hip/hip_runtime.h>

// Adaptive avg pool (16,2048,64,64) fp32 -> (16,2048,6,6).
// One wave handles 4 planes: lane = ps*16 + q  (ps = plane-sub 0..3,
// q = column-quad 0..15, i.e. cols 4q..4q+3 as a float4).
// Phase A: h = 0..63 fully unrolled; per h one global_load_dwordx4 per lane
//   (wave covers row h of 4 planes = 4x256B dense segments). Row->h-bin
//   membership is compile-time (rows 10,21,42,53 feed two bins), accumulated
//   into 6 float4 registers. Exactly 16 wave-loads per plane, zero over-read,
//   no big LDS tile.
// Phase B: dump acc to a small per-wave LDS block (bin-row stride 68 to
//   de-alias banks), one barrier, 144 tasks/wave do the w-bin reduction
//   (~11.5 scalar LDS reads each), scale, store.
// Grid: 32768 planes / 16 per block = 2048 blocks. LDS 25.5 KiB/block ->
// 6 blocks/CU (24 waves), each wave with up to 64 loads in flight.

#define HW 64
#define NOUT 6
#define NP 4          // planes per wave
#define CSTR 68       // padded column stride per bin row

__global__ __launch_bounds__(256)
void adaptive_pool_kernel(const float* __restrict__ x, float* __restrict__ out) {
    __shared__ float lds[4][NP][NOUT * CSTR];   // 4*4*6*68*4 B = 26112 B

    const int tid  = threadIdx.x;
    const int wave = tid >> 6;
    const int lane = tid & 63;
    const int ps   = lane >> 4;      // plane-sub within wave
    const int q    = lane & 15;      // column quad

    const int plane0 = (blockIdx.x * 4 + wave) * NP;
    const float* __restrict__ src =
        x + (size_t)(plane0 + ps) * (HW * HW) + q * 4;

    constexpr int bs[NOUT] = {0, 10, 21, 32, 42, 53};
    constexpr int be[NOUT] = {11, 22, 32, 43, 54, 64};

    // ---- Phase A: register h-bin accumulation, compile-time bins ----
    float4 acc[NOUT];
    #pragma unroll
    for (int i = 0; i < NOUT; ++i) acc[i] = make_float4(0.f, 0.f, 0.f, 0.f);

    #pragma unroll
    for (int h = 0; h < HW; ++h) {
        float4 v = *(const float4*)(src + h * HW);
        #pragma unroll
        for (int i = 0; i < NOUT; ++i) {
            if (h >= bs[i] && h < be[i]) {     // folds at compile time
                acc[i].x += v.x; acc[i].y += v.y;
                acc[i].z += v.z; acc[i].w += v.w;
            }
        }
    }

    // dump per-column h-bin sums to LDS: [ps][bin][col], stride CSTR
    #pragma unroll
    for (int i = 0; i < NOUT; ++i)
        *(float4*)&lds[wave][ps][i * CSTR + q * 4] = acc[i];
    __syncthreads();

    // ---- Phase B: w-bin reduction: 144 outputs per wave ----
    for (int t = lane; t < NP * NOUT * NOUT; t += 64) {
        int p  = t / (NOUT * NOUT);            // plane-sub 0..3
        int r  = t - p * (NOUT * NOUT);        // 0..35
        int i  = r / NOUT;
        int j  = r - i * NOUT;
        const float* c = &lds[wave][p][i * CSTR];
        float s = 0.f;
        for (int w = bs[j]; w < be[j]; ++w)
            s += c[w];
        float scale = 1.0f / (float)((be[i] - bs[i]) * (be[j] - bs[j]));
        out[(size_t)(plane0 + p) * (NOUT * NOUT) + r] = s * scale;
    }
}

extern "C" void kernel_launch(void* const* d_in, const int* in_sizes, int n_in,
                              void* d_out, int out_size, void* d_ws, size_t ws_size,
                              hipStream_t stream) {
    const float* x = (const float*)d_in[0];
    float* out = (float*)d_out;
    const int n_planes = in_sizes[0] / (HW * HW);            // 32768
    const int n_blocks = n_planes / (4 * NP);                // 2048
    adaptive_pool_kernel<<<n_blocks, 256, 0, stream>>>(x, out);
}